// Round 5
// baseline (1299.069 us; speedup 1.0000x reference)
//
#include <hip/hip_runtime.h>

#define NUM_USERS 100000
#define NUM_ITEMS 200000
#define NT        300000        // NUM_USERS + NUM_ITEMS
#define D         64
#define NNZ_C     4000000
#define BATCH     16384

#define RPB_LOG   8
#define RPB       256                       // rows per bucket
#define NBUCK     ((NT + RPB - 1) / RPB)    // 1172
#define BCAP      4096                      // mean 3413/bucket, sigma~58 -> 11.7 sigma margin

// ---------------------------------------------------------------------------
// Phase 1: append edges into per-bucket arrays (sequential per-bucket streams,
// so writes fill cache lines -> no write amplification).
// entry.x = col | (row&255)<<19   (col < 2^19), entry.y = bits(val)
// ---------------------------------------------------------------------------
__global__ void bucket_scatter(const int* __restrict__ row, const int* __restrict__ col,
                               const float* __restrict__ val, int* __restrict__ bcnt,
                               int2* __restrict__ entries) {
    int stride = gridDim.x * blockDim.x;
    for (int e = blockIdx.x * blockDim.x + threadIdx.x; e < NNZ_C; e += stride) {
        int r = row[e];
        int b = r >> RPB_LOG;
        int pos = atomicAdd(&bcnt[b], 1);
        if (pos < BCAP)
            entries[(long)b * BCAP + pos] =
                make_int2(col[e] | ((r & (RPB - 1)) << 19), __float_as_int(val[e]));
    }
}

// ---------------------------------------------------------------------------
// Small scan over NBUCK bucket counts (2 blocks of 1024 + partials fixup)
// ---------------------------------------------------------------------------
__global__ void scan_block_n(const int* __restrict__ in, int* __restrict__ outExcl,
                             int* __restrict__ partials, int n) {
    __shared__ int s[1024];
    int tid = threadIdx.x;
    int idx = blockIdx.x * 1024 + tid;
    int v = (idx < n) ? in[idx] : 0;
    int acc = v;
    s[tid] = acc; __syncthreads();
    for (int off = 1; off < 1024; off <<= 1) {
        int t = (tid >= off) ? s[tid - off] : 0;
        __syncthreads();
        acc += t; s[tid] = acc; __syncthreads();
    }
    if (idx < n) outExcl[idx] = acc - v;
    if (tid == 1023) partials[blockIdx.x] = acc;
}

__global__ void scan_partials_n(int* __restrict__ partials, int nblk) {
    __shared__ int s[1024];
    int tid = threadIdx.x;
    int v = (tid < nblk) ? partials[tid] : 0;
    int acc = v;
    s[tid] = acc; __syncthreads();
    for (int off = 1; off < 1024; off <<= 1) {
        int t = (tid >= off) ? s[tid - off] : 0;
        __syncthreads();
        acc += t; s[tid] = acc; __syncthreads();
    }
    if (tid < nblk) partials[tid] = acc - v;
}

__global__ void add_offsets_n(int* __restrict__ outExcl, const int* __restrict__ partials,
                              int n, int* __restrict__ rowstart_last) {
    int idx = blockIdx.x * 1024 + threadIdx.x;
    if (idx < n) outExcl[idx] += partials[blockIdx.x];
    if (idx == 0) rowstart_last[0] = NNZ_C;   // rowstart[NT] = NNZ
}

// ---------------------------------------------------------------------------
// Phase 2: one block per bucket. LDS histogram of the 256 rows -> LDS scan
// (produces rowstart for free) -> scatter entries to exact cv slots.
// All cv writes land in a ~27KB L2-resident window per block.
// ---------------------------------------------------------------------------
__global__ void build_rows_csr(const int* __restrict__ bcnt, const int* __restrict__ bucketstart,
                               const int2* __restrict__ entries, int* __restrict__ rowstart,
                               int2* __restrict__ cv) {
    __shared__ int s[RPB];
    __shared__ int cur[RPB];
    int b = blockIdx.x, tid = threadIdx.x;
    int n = bcnt[b]; if (n > BCAP) n = BCAP;
    const int2* ebase = entries + (long)b * BCAP;

    s[tid] = 0;
    __syncthreads();
    for (int k = tid; k < n; k += RPB)
        atomicAdd(&s[((unsigned)ebase[k].x) >> 19], 1);
    __syncthreads();
    int v = s[tid];
    int acc = v;
    __syncthreads();
    for (int off = 1; off < RPB; off <<= 1) {
        int t = (tid >= off) ? s[tid - off] : 0;
        __syncthreads();
        acc += t; s[tid] = acc; __syncthreads();
    }
    int rs = bucketstart[b] + (acc - v);      // global CSR start of this row
    int grow = b * RPB + tid;
    if (grow < NT) rowstart[grow] = rs;
    cur[tid] = rs;
    __syncthreads();
    for (int k = tid; k < n; k += RPB) {
        int2 e = ebase[k];
        int rl = ((unsigned)e.x) >> 19;
        int p = atomicAdd(&cur[rl], 1);
        cv[p] = make_int2(e.x & 0x7FFFF, e.y);
    }
}

// ---------------------------------------------------------------------------
// CSR SpMM (gather): one 64-lane wave per row, lane = output dim, unroll 4.
// CAT=true reads the virtual concat(uw,iw) as x (skips materializing x0).
// ---------------------------------------------------------------------------
template <bool CAT>
__device__ inline float ldx(const float* __restrict__ x, const float* __restrict__ uw,
                            const float* __restrict__ iw, int c, int lane) {
    if (CAT) {
        const float* p = (c < NUM_USERS) ? (uw + (long)c * D)
                                         : (iw + (long)(c - NUM_USERS) * D);
        return p[lane];
    }
    return x[(long)c * D + lane];
}

template <bool CAT>
__global__ void csr_spmm_k(const int* __restrict__ rowstart, const int2* __restrict__ cv,
                           const float* __restrict__ x, const float* __restrict__ uw,
                           const float* __restrict__ iw, float* __restrict__ y) {
    int r = blockIdx.x * 4 + (threadIdx.x >> 6);
    int lane = threadIdx.x & 63;
    if (r >= NT) return;
    int s = rowstart[r], e = rowstart[r + 1];
    float a0 = 0.f, a1 = 0.f, a2 = 0.f, a3 = 0.f;
    int j = s;
    for (; j + 4 <= e; j += 4) {
        int2 c0 = cv[j], c1 = cv[j + 1], c2 = cv[j + 2], c3 = cv[j + 3];
        a0 += __int_as_float(c0.y) * ldx<CAT>(x, uw, iw, c0.x, lane);
        a1 += __int_as_float(c1.y) * ldx<CAT>(x, uw, iw, c1.x, lane);
        a2 += __int_as_float(c2.y) * ldx<CAT>(x, uw, iw, c2.x, lane);
        a3 += __int_as_float(c3.y) * ldx<CAT>(x, uw, iw, c3.x, lane);
    }
    if (j + 2 <= e) {
        int2 c0 = cv[j], c1 = cv[j + 1];
        a0 += __int_as_float(c0.y) * ldx<CAT>(x, uw, iw, c0.x, lane);
        a1 += __int_as_float(c1.y) * ldx<CAT>(x, uw, iw, c1.x, lane);
        j += 2;
    }
    if (j < e) {
        int2 c0 = cv[j];
        a0 += __int_as_float(c0.y) * ldx<CAT>(x, uw, iw, c0.x, lane);
    }
    y[(long)r * D + lane] = (a0 + a1) + (a2 + a3);
}

// ---------------------------------------------------------------------------
// Layer-3 SpMM only at the 2*BATCH needed rows, accumulated into acc.
// ---------------------------------------------------------------------------
__global__ void csr_spmm_acc(const int* __restrict__ uid, const int* __restrict__ iid,
                             const int* __restrict__ rowstart, const int2* __restrict__ cv,
                             const float* __restrict__ x, float* __restrict__ acc) {
    int b = blockIdx.x * 4 + (threadIdx.x >> 6);
    int lane = threadIdx.x & 63;
    if (b >= 2 * BATCH) return;
    int r = (b < BATCH) ? uid[b] : (iid[b - BATCH] + NUM_USERS);
    int s = rowstart[r], e = rowstart[r + 1];
    float a0 = 0.f, a1 = 0.f;
    int j = s;
    for (; j + 2 <= e; j += 2) {
        int2 c0 = cv[j], c1 = cv[j + 1];
        a0 += __int_as_float(c0.y) * x[(long)c0.x * D + lane];
        a1 += __int_as_float(c1.y) * x[(long)c1.x * D + lane];
    }
    if (j < e) {
        int2 c0 = cv[j];
        a0 += __int_as_float(c0.y) * x[(long)c0.x * D + lane];
    }
    acc[(long)b * D + lane] += a0 + a1;
}

// ---------------------------------------------------------------------------
// gather_init: acc = layer-0 embedding (virtual concat) at batch rows.
// gather_acc: acc += layer embedding at batch rows.
// ---------------------------------------------------------------------------
__global__ void gather_init(const int* __restrict__ uid, const int* __restrict__ iid,
                            const float* __restrict__ uw, const float* __restrict__ iw,
                            float* __restrict__ acc) {
    int t = blockIdx.x * blockDim.x + threadIdx.x;      // exact: 2*BATCH*16
    int b   = t >> 4;
    int sub = t & 15;
    const float* src = (b < BATCH) ? (uw + (long)uid[b] * D)
                                   : (iw + (long)iid[b - BATCH] * D);
    ((float4*)(acc + (long)b * D))[sub] = ((const float4*)src)[sub];
}

__global__ void gather_acc(const int* __restrict__ uid, const int* __restrict__ iid,
                           const float* __restrict__ x, float* __restrict__ acc) {
    int t = blockIdx.x * blockDim.x + threadIdx.x;      // exact: 2*BATCH*16
    int b   = t >> 4;
    int sub = t & 15;
    int r   = (b < BATCH) ? uid[b] : (iid[b - BATCH] + NUM_USERS);
    float4 g = *((const float4*)(x + (long)r * D) + sub);
    float4* a = (float4*)(acc + (long)b * D) + sub;
    float4 p = *a;
    p.x += g.x; p.y += g.y; p.z += g.z; p.w += g.w;
    *a = p;
}

// ---------------------------------------------------------------------------
// final: out[b] = dot(accU[b], accI[b]) / 16
// ---------------------------------------------------------------------------
__global__ void final_dot(const float* __restrict__ acc, float* __restrict__ out) {
    int t = blockIdx.x * blockDim.x + threadIdx.x;      // exact: BATCH*16
    int b   = t >> 4;
    int sub = t & 15;
    float4 u = *((const float4*)(acc + (long)b * D) + sub);
    float4 w = *((const float4*)(acc + (long)(b + BATCH) * D) + sub);
    float p = u.x * w.x + u.y * w.y + u.z * w.z + u.w * w.w;
    p += __shfl_xor(p, 1);
    p += __shfl_xor(p, 2);
    p += __shfl_xor(p, 4);
    p += __shfl_xor(p, 8);
    if (sub == 0) out[b] = p * (1.0f / 16.0f);
}

extern "C" void kernel_launch(void* const* d_in, const int* in_sizes, int n_in,
                              void* d_out, int out_size, void* d_ws, size_t ws_size,
                              hipStream_t stream) {
    const int*   user_ids = (const int*)d_in[0];
    const int*   item_ids = (const int*)d_in[1];
    const int*   adj_row  = (const int*)d_in[2];
    const int*   adj_col  = (const int*)d_in[3];
    const float* adj_val  = (const float*)d_in[4];
    const float* uw       = (const float*)d_in[5];
    const float* iw       = (const float*)d_in[6];
    float*       out      = (float*)d_out;

    // workspace bump allocator (256B aligned); total ~195.3 MB (<=197MB proven OK)
    char* ws = (char*)d_ws;
    size_t off = 0;
    auto alloc = [&](size_t bytes) {
        char* p = ws + off;
        off += (bytes + 255) & ~(size_t)255;
        return p;
    };
    const size_t xbytes = (size_t)NT * D * sizeof(float);                   // 76.8 MB
    float* xA          = (float*)alloc(xbytes);
    float* xB          = (float*)alloc(xbytes);                             // also hosts entries
    float* acc         = (float*)alloc((size_t)2 * BATCH * D * sizeof(float)); // 8.4 MB
    int*   rowstart    = (int*)alloc((size_t)(NT + 1) * sizeof(int));
    int*   bcnt        = (int*)alloc((size_t)NBUCK * sizeof(int));
    int*   bucketstart = (int*)alloc((size_t)NBUCK * sizeof(int));
    int*   partials    = (int*)alloc(1024 * sizeof(int));
    int2*  cv          = (int2*)alloc((size_t)NNZ_C * sizeof(int2));        // 32 MB
    int2*  entries     = (int2*)xB;   // 38.4 MB, dead before xB is first written

    // ---- bucketed CSR build ----
    hipMemsetAsync(bcnt, 0, (size_t)NBUCK * sizeof(int), stream);
    bucket_scatter<<<2048, 256, 0, stream>>>(adj_row, adj_col, adj_val, bcnt, entries);
    scan_block_n<<<(NBUCK + 1023) / 1024, 1024, 0, stream>>>(bcnt, bucketstart, partials, NBUCK);
    scan_partials_n<<<1, 1024, 0, stream>>>(partials, (NBUCK + 1023) / 1024);
    add_offsets_n<<<(NBUCK + 1023) / 1024, 1024, 0, stream>>>(bucketstart, partials, NBUCK,
                                                              rowstart + NT);
    build_rows_csr<<<NBUCK, RPB, 0, stream>>>(bcnt, bucketstart, entries, rowstart, cv);

    // ---- layer pipeline ----
    gather_init<<<(2 * BATCH * 16) / 256, 256, 0, stream>>>(user_ids, item_ids, uw, iw, acc);

    // layer 1: reads virtual concat(uw,iw), writes xA
    csr_spmm_k<true><<<(NT + 3) / 4, 256, 0, stream>>>(rowstart, cv, nullptr, uw, iw, xA);
    gather_acc<<<(2 * BATCH * 16) / 256, 256, 0, stream>>>(user_ids, item_ids, xA, acc);

    // layer 2: xA -> xB (entries dead by now)
    csr_spmm_k<false><<<(NT + 3) / 4, 256, 0, stream>>>(rowstart, cv, xA, nullptr, nullptr, xB);
    gather_acc<<<(2 * BATCH * 16) / 256, 256, 0, stream>>>(user_ids, item_ids, xB, acc);

    // layer 3: only the 2*BATCH needed rows, straight into acc
    csr_spmm_acc<<<(2 * BATCH + 3) / 4, 256, 0, stream>>>(user_ids, item_ids,
                                                          rowstart, cv, xB, acc);

    final_dot<<<(BATCH * 16) / 256, 256, 0, stream>>>(acc, out);
}

// Round 6
// 661.795 us; speedup vs baseline: 1.9629x; 1.9629x over previous
//
#include <hip/hip_runtime.h>

#define NUM_USERS 100000
#define NUM_ITEMS 200000
#define NT        300000        // NUM_USERS + NUM_ITEMS
#define D         64
#define NNZ_C     4000000
#define BATCH     16384

// bucketing: 1024 rows per super-bucket
#define SB_LOG    10
#define SB_ROWS   1024
#define NSB       ((NT + SB_ROWS - 1) / SB_ROWS)   // 293
#define SBCAP     16384                            // mean 13.65K, sigma~116 -> 23 sigma margin
#define CHUNK     8192
#define NCHUNK    ((NNZ_C + CHUNK - 1) / CHUNK)    // 489

// ---------------------------------------------------------------------------
// Phase 1: bin edges into NSB bucket arrays. Per-chunk LDS histogram ->
// ONE bulk global atomicAdd per (chunk,bin) (143K atomics total, no
// contention) -> per-edge LDS-cursor placement. Each chunk writes ~224B
// contiguous per bin from one block/XCD -> lines fill in one L2.
// entry.x = col | (row&1023)<<19  (col < 2^19), entry.y = bits(val)
// ---------------------------------------------------------------------------
__global__ void p1_bin(const int* __restrict__ row, const int* __restrict__ col,
                       const float* __restrict__ val, int* __restrict__ bcnt,
                       int2* __restrict__ entries) {
    __shared__ int hist[NSB];
    __shared__ int cur[NSB];
    int tid = threadIdx.x;                       // 512
    long cb = (long)blockIdx.x * CHUNK;
    int n = (int)((NNZ_C - cb < CHUNK) ? (NNZ_C - cb) : CHUNK);
    for (int i = tid; i < NSB; i += 512) hist[i] = 0;
    __syncthreads();
    for (int k = tid; k < n; k += 512)
        atomicAdd(&hist[row[cb + k] >> SB_LOG], 1);
    __syncthreads();
    for (int i = tid; i < NSB; i += 512)
        cur[i] = atomicAdd(&bcnt[i], hist[i]);   // bulk reservation
    __syncthreads();
    for (int k = tid; k < n; k += 512) {
        int r = row[cb + k];
        int b = r >> SB_LOG;
        int pos = atomicAdd(&cur[b], 1);
        if (pos < SBCAP)
            entries[(long)b * SBCAP + pos] =
                make_int2(col[cb + k] | ((r & (SB_ROWS - 1)) << 19),
                          __float_as_int(val[cb + k]));
    }
}

// ---------------------------------------------------------------------------
// Scan over NSB bucket totals (1 block). Also sets rowstart[NT] = NNZ.
// ---------------------------------------------------------------------------
__global__ void bucket_scan(const int* __restrict__ bcnt, int* __restrict__ bucketstart,
                            int* __restrict__ rowstart) {
    __shared__ int s[512];
    int tid = threadIdx.x;
    int v = (tid < NSB) ? min(bcnt[tid], SBCAP) : 0;
    int acc = v;
    s[tid] = acc; __syncthreads();
    for (int off = 1; off < 512; off <<= 1) {
        int t = (tid >= off) ? s[tid - off] : 0;
        __syncthreads();
        acc += t; s[tid] = acc; __syncthreads();
    }
    if (tid < NSB) bucketstart[tid] = acc - v;
    if (tid == 0) rowstart[NT] = s[511];
}

// ---------------------------------------------------------------------------
// Phase 2: one block per bucket. LDS histogram of 1024 rows -> LDS scan
// (produces rowstart for free) -> scatter to exact cv slots. All cv writes
// land in a ~110KB L2-resident window per block -> no write amplification.
// ---------------------------------------------------------------------------
__global__ void p2_csr(const int* __restrict__ bcnt, const int* __restrict__ bucketstart,
                       const int2* __restrict__ entries, int* __restrict__ rowstart,
                       int2* __restrict__ cv) {
    __shared__ int h[SB_ROWS];
    __shared__ int cur[SB_ROWS];
    int b = blockIdx.x, tid = threadIdx.x;       // 1024 threads
    int n = min(bcnt[b], SBCAP);
    const int2* eb = entries + (long)b * SBCAP;
    h[tid] = 0; __syncthreads();
    for (int k = tid; k < n; k += SB_ROWS)
        atomicAdd(&h[((unsigned)eb[k].x) >> 19], 1);
    __syncthreads();
    int v = h[tid];
    int acc = v;
    __syncthreads();
    for (int off = 1; off < SB_ROWS; off <<= 1) {
        int t = (tid >= off) ? h[tid - off] : 0;
        __syncthreads();
        acc += t; h[tid] = acc; __syncthreads();
    }
    int rs = bucketstart[b] + (acc - v);         // global CSR start of this row
    int grow = (b << SB_LOG) + tid;
    if (grow < NT) rowstart[grow] = rs;
    cur[tid] = rs;
    __syncthreads();
    for (int k = tid; k < n; k += SB_ROWS) {
        int2 e = eb[k];
        int rl = ((unsigned)e.x) >> 19;
        int p = atomicAdd(&cur[rl], 1);
        cv[p] = make_int2(e.x & 0x7FFFF, e.y);
    }
}

// ---------------------------------------------------------------------------
// CSR SpMM (gather): one 64-lane wave per row, lane = output dim, unroll 4.
// CAT=true reads the virtual concat(uw,iw) as x (skips materializing x0).
// ---------------------------------------------------------------------------
template <bool CAT>
__device__ inline float ldx(const float* __restrict__ x, const float* __restrict__ uw,
                            const float* __restrict__ iw, int c, int lane) {
    if (CAT) {
        const float* p = (c < NUM_USERS) ? (uw + (long)c * D)
                                         : (iw + (long)(c - NUM_USERS) * D);
        return p[lane];
    }
    return x[(long)c * D + lane];
}

template <bool CAT>
__global__ void csr_spmm_k(const int* __restrict__ rowstart, const int2* __restrict__ cv,
                           const float* __restrict__ x, const float* __restrict__ uw,
                           const float* __restrict__ iw, float* __restrict__ y) {
    int r = blockIdx.x * 4 + (threadIdx.x >> 6);
    int lane = threadIdx.x & 63;
    if (r >= NT) return;
    int s = rowstart[r], e = rowstart[r + 1];
    float a0 = 0.f, a1 = 0.f, a2 = 0.f, a3 = 0.f;
    int j = s;
    for (; j + 4 <= e; j += 4) {
        int2 c0 = cv[j], c1 = cv[j + 1], c2 = cv[j + 2], c3 = cv[j + 3];
        a0 += __int_as_float(c0.y) * ldx<CAT>(x, uw, iw, c0.x, lane);
        a1 += __int_as_float(c1.y) * ldx<CAT>(x, uw, iw, c1.x, lane);
        a2 += __int_as_float(c2.y) * ldx<CAT>(x, uw, iw, c2.x, lane);
        a3 += __int_as_float(c3.y) * ldx<CAT>(x, uw, iw, c3.x, lane);
    }
    if (j + 2 <= e) {
        int2 c0 = cv[j], c1 = cv[j + 1];
        a0 += __int_as_float(c0.y) * ldx<CAT>(x, uw, iw, c0.x, lane);
        a1 += __int_as_float(c1.y) * ldx<CAT>(x, uw, iw, c1.x, lane);
        j += 2;
    }
    if (j < e) {
        int2 c0 = cv[j];
        a0 += __int_as_float(c0.y) * ldx<CAT>(x, uw, iw, c0.x, lane);
    }
    y[(long)r * D + lane] = (a0 + a1) + (a2 + a3);
}

// ---------------------------------------------------------------------------
// Layer-3 SpMM only at the 2*BATCH needed rows, accumulated into acc.
// ---------------------------------------------------------------------------
__global__ void csr_spmm_acc(const int* __restrict__ uid, const int* __restrict__ iid,
                             const int* __restrict__ rowstart, const int2* __restrict__ cv,
                             const float* __restrict__ x, float* __restrict__ acc) {
    int b = blockIdx.x * 4 + (threadIdx.x >> 6);
    int lane = threadIdx.x & 63;
    if (b >= 2 * BATCH) return;
    int r = (b < BATCH) ? uid[b] : (iid[b - BATCH] + NUM_USERS);
    int s = rowstart[r], e = rowstart[r + 1];
    float a0 = 0.f, a1 = 0.f;
    int j = s;
    for (; j + 2 <= e; j += 2) {
        int2 c0 = cv[j], c1 = cv[j + 1];
        a0 += __int_as_float(c0.y) * x[(long)c0.x * D + lane];
        a1 += __int_as_float(c1.y) * x[(long)c1.x * D + lane];
    }
    if (j < e) {
        int2 c0 = cv[j];
        a0 += __int_as_float(c0.y) * x[(long)c0.x * D + lane];
    }
    acc[(long)b * D + lane] += a0 + a1;
}

// ---------------------------------------------------------------------------
// gather_init / gather_acc at the 2*BATCH batch rows.
// ---------------------------------------------------------------------------
__global__ void gather_init(const int* __restrict__ uid, const int* __restrict__ iid,
                            const float* __restrict__ uw, const float* __restrict__ iw,
                            float* __restrict__ acc) {
    int t = blockIdx.x * blockDim.x + threadIdx.x;      // exact: 2*BATCH*16
    int b   = t >> 4;
    int sub = t & 15;
    const float* src = (b < BATCH) ? (uw + (long)uid[b] * D)
                                   : (iw + (long)iid[b - BATCH] * D);
    ((float4*)(acc + (long)b * D))[sub] = ((const float4*)src)[sub];
}

__global__ void gather_acc(const int* __restrict__ uid, const int* __restrict__ iid,
                           const float* __restrict__ x, float* __restrict__ acc) {
    int t = blockIdx.x * blockDim.x + threadIdx.x;      // exact: 2*BATCH*16
    int b   = t >> 4;
    int sub = t & 15;
    int r   = (b < BATCH) ? uid[b] : (iid[b - BATCH] + NUM_USERS);
    float4 g = *((const float4*)(x + (long)r * D) + sub);
    float4* a = (float4*)(acc + (long)b * D) + sub;
    float4 p = *a;
    p.x += g.x; p.y += g.y; p.z += g.z; p.w += g.w;
    *a = p;
}

// ---------------------------------------------------------------------------
// final: out[b] = dot(accU[b], accI[b]) / 16
// ---------------------------------------------------------------------------
__global__ void final_dot(const float* __restrict__ acc, float* __restrict__ out) {
    int t = blockIdx.x * blockDim.x + threadIdx.x;      // exact: BATCH*16
    int b   = t >> 4;
    int sub = t & 15;
    float4 u = *((const float4*)(acc + (long)b * D) + sub);
    float4 w = *((const float4*)(acc + (long)(b + BATCH) * D) + sub);
    float p = u.x * w.x + u.y * w.y + u.z * w.z + u.w * w.w;
    p += __shfl_xor(p, 1);
    p += __shfl_xor(p, 2);
    p += __shfl_xor(p, 4);
    p += __shfl_xor(p, 8);
    if (sub == 0) out[b] = p * (1.0f / 16.0f);
}

extern "C" void kernel_launch(void* const* d_in, const int* in_sizes, int n_in,
                              void* d_out, int out_size, void* d_ws, size_t ws_size,
                              hipStream_t stream) {
    const int*   user_ids = (const int*)d_in[0];
    const int*   item_ids = (const int*)d_in[1];
    const int*   adj_row  = (const int*)d_in[2];
    const int*   adj_col  = (const int*)d_in[3];
    const float* adj_val  = (const float*)d_in[4];
    const float* uw       = (const float*)d_in[5];
    const float* iw       = (const float*)d_in[6];
    float*       out      = (float*)d_out;

    // workspace bump allocator (256B aligned); total ~195.3 MB (proven OK round 4)
    char* ws = (char*)d_ws;
    size_t off = 0;
    auto alloc = [&](size_t bytes) {
        char* p = ws + off;
        off += (bytes + 255) & ~(size_t)255;
        return p;
    };
    const size_t xbytes = (size_t)NT * D * sizeof(float);                   // 76.8 MB
    float* xA          = (float*)alloc(xbytes);
    float* xB          = (float*)alloc(xbytes);                             // also hosts entries
    float* acc         = (float*)alloc((size_t)2 * BATCH * D * sizeof(float)); // 8.4 MB
    int*   rowstart    = (int*)alloc((size_t)(NT + 1) * sizeof(int));
    int*   bcnt        = (int*)alloc((size_t)NSB * sizeof(int));
    int*   bucketstart = (int*)alloc((size_t)NSB * sizeof(int));
    int2*  cv          = (int2*)alloc((size_t)NNZ_C * sizeof(int2));        // 32 MB
    int2*  entries     = (int2*)xB;   // 293*16384*8 = 38.4 MB, dead before xB written

    // ---- bucketed CSR build ----
    hipMemsetAsync(bcnt, 0, (size_t)NSB * sizeof(int), stream);
    p1_bin<<<NCHUNK, 512, 0, stream>>>(adj_row, adj_col, adj_val, bcnt, entries);
    bucket_scan<<<1, 512, 0, stream>>>(bcnt, bucketstart, rowstart);
    p2_csr<<<NSB, SB_ROWS, 0, stream>>>(bcnt, bucketstart, entries, rowstart, cv);

    // ---- layer pipeline ----
    gather_init<<<(2 * BATCH * 16) / 256, 256, 0, stream>>>(user_ids, item_ids, uw, iw, acc);

    // layer 1: reads virtual concat(uw,iw), writes xA
    csr_spmm_k<true><<<(NT + 3) / 4, 256, 0, stream>>>(rowstart, cv, nullptr, uw, iw, xA);
    gather_acc<<<(2 * BATCH * 16) / 256, 256, 0, stream>>>(user_ids, item_ids, xA, acc);

    // layer 2: xA -> xB (entries dead by now)
    csr_spmm_k<false><<<(NT + 3) / 4, 256, 0, stream>>>(rowstart, cv, xA, nullptr, nullptr, xB);
    gather_acc<<<(2 * BATCH * 16) / 256, 256, 0, stream>>>(user_ids, item_ids, xB, acc);

    // layer 3: only the 2*BATCH needed rows, straight into acc
    csr_spmm_acc<<<(2 * BATCH + 3) / 4, 256, 0, stream>>>(user_ids, item_ids,
                                                          rowstart, cv, xB, acc);

    final_dot<<<(BATCH * 16) / 256, 256, 0, stream>>>(acc, out);
}

// Round 7
// 633.181 us; speedup vs baseline: 2.0517x; 1.0452x over previous
//
#include <hip/hip_runtime.h>

#define NUM_USERS 100000
#define NUM_ITEMS 200000
#define NT        300000        // NUM_USERS + NUM_ITEMS
#define D         64
#define NNZ_C     4000000
#define BATCH     16384

// bucketing: 1024 rows per super-bucket
#define SB_LOG    10
#define SB_ROWS   1024
#define NSB       ((NT + SB_ROWS - 1) / SB_ROWS)   // 293
#define SBCAP     16384                            // mean 13.65K, sigma~116 -> 23 sigma margin
#define CHUNK     8192
#define NCHUNK    ((NNZ_C + CHUNK - 1) / CHUNK)    // 489

// ---------------------------------------------------------------------------
// Phase 1: bin edges into NSB bucket arrays. Per-chunk LDS histogram ->
// ONE bulk global atomicAdd per (chunk,bin) -> per-edge LDS-cursor placement.
// entry.x = col | (row&1023)<<19  (col < 2^19), entry.y = bits(val)
// ---------------------------------------------------------------------------
__global__ void p1_bin(const int* __restrict__ row, const int* __restrict__ col,
                       const float* __restrict__ val, int* __restrict__ bcnt,
                       int2* __restrict__ entries) {
    __shared__ int hist[NSB];
    __shared__ int cur[NSB];
    int tid = threadIdx.x;                       // 512
    long cb = (long)blockIdx.x * CHUNK;
    int n = (int)((NNZ_C - cb < CHUNK) ? (NNZ_C - cb) : CHUNK);
    for (int i = tid; i < NSB; i += 512) hist[i] = 0;
    __syncthreads();
    for (int k = tid; k < n; k += 512)
        atomicAdd(&hist[row[cb + k] >> SB_LOG], 1);
    __syncthreads();
    for (int i = tid; i < NSB; i += 512)
        cur[i] = atomicAdd(&bcnt[i], hist[i]);   // bulk reservation
    __syncthreads();
    for (int k = tid; k < n; k += 512) {
        int r = row[cb + k];
        int b = r >> SB_LOG;
        int pos = atomicAdd(&cur[b], 1);
        if (pos < SBCAP)
            entries[(long)b * SBCAP + pos] =
                make_int2(col[cb + k] | ((r & (SB_ROWS - 1)) << 19),
                          __float_as_int(val[cb + k]));
    }
}

// ---------------------------------------------------------------------------
// Scan over NSB bucket totals (1 block). Also sets rowstart[NT] = NNZ.
// ---------------------------------------------------------------------------
__global__ void bucket_scan(const int* __restrict__ bcnt, int* __restrict__ bucketstart,
                            int* __restrict__ rowstart) {
    __shared__ int s[512];
    int tid = threadIdx.x;
    int v = (tid < NSB) ? min(bcnt[tid], SBCAP) : 0;
    int acc = v;
    s[tid] = acc; __syncthreads();
    for (int off = 1; off < 512; off <<= 1) {
        int t = (tid >= off) ? s[tid - off] : 0;
        __syncthreads();
        acc += t; s[tid] = acc; __syncthreads();
    }
    if (tid < NSB) bucketstart[tid] = acc - v;
    if (tid == 0) rowstart[NT] = s[511];
}

// ---------------------------------------------------------------------------
// Phase 2: one block per bucket. LDS histogram of 1024 rows -> LDS scan
// (produces rowstart for free) -> scatter to exact cv slots (L2-resident
// ~110KB window per block -> no write amplification).
// ---------------------------------------------------------------------------
__global__ void p2_csr(const int* __restrict__ bcnt, const int* __restrict__ bucketstart,
                       const int2* __restrict__ entries, int* __restrict__ rowstart,
                       int2* __restrict__ cv) {
    __shared__ int h[SB_ROWS];
    __shared__ int cur[SB_ROWS];
    int b = blockIdx.x, tid = threadIdx.x;       // 1024 threads
    int n = min(bcnt[b], SBCAP);
    const int2* eb = entries + (long)b * SBCAP;
    h[tid] = 0; __syncthreads();
    for (int k = tid; k < n; k += SB_ROWS)
        atomicAdd(&h[((unsigned)eb[k].x) >> 19], 1);
    __syncthreads();
    int v = h[tid];
    int acc = v;
    __syncthreads();
    for (int off = 1; off < SB_ROWS; off <<= 1) {
        int t = (tid >= off) ? h[tid - off] : 0;
        __syncthreads();
        acc += t; h[tid] = acc; __syncthreads();
    }
    int rs = bucketstart[b] + (acc - v);         // global CSR start of this row
    int grow = (b << SB_LOG) + tid;
    if (grow < NT) rowstart[grow] = rs;
    cur[tid] = rs;
    __syncthreads();
    for (int k = tid; k < n; k += SB_ROWS) {
        int2 e = eb[k];
        int rl = ((unsigned)e.x) >> 19;
        int p = atomicAdd(&cur[rl], 1);
        cv[p] = make_int2(e.x & 0x7FFFF, e.y);
    }
}

// ---------------------------------------------------------------------------
// mark rows needed from layer 2: batch rows + their edge columns.
// ---------------------------------------------------------------------------
__global__ void mark_needed(const int* __restrict__ uid, const int* __restrict__ iid,
                            const int* __restrict__ rowstart, const int2* __restrict__ cv,
                            char* __restrict__ flags) {
    int t = blockIdx.x * blockDim.x + threadIdx.x;   // exact: 2*BATCH
    int r = (t < BATCH) ? uid[t] : (iid[t - BATCH] + NUM_USERS);
    flags[r] = 1;
    int e = rowstart[r + 1];
    for (int j = rowstart[r]; j < e; ++j)
        flags[cv[j].x] = 1;
}

// ---------------------------------------------------------------------------
// CSR SpMM (gather): one 64-lane wave per row. lane = (grp = edge slot,
// sub = dim quarter); each float4 load instr covers 4 edges (1KB).
// Final shfl_xor(16/32) reduces the 4 edge-groups; grp 0 stores float4.
// CAT: read virtual concat(uw,iw) as x. FILT: skip rows with flag==0.
// ---------------------------------------------------------------------------
template <bool CAT, bool FILT>
__global__ void csr_spmm_k(const int* __restrict__ rowstart, const int2* __restrict__ cv,
                           const float* __restrict__ x, const float* __restrict__ uw,
                           const float* __restrict__ iw, const char* __restrict__ flags,
                           float* __restrict__ y) {
    int r = blockIdx.x * 4 + (threadIdx.x >> 6);
    if (r >= NT) return;
    if (FILT && !flags[r]) return;
    int lane = threadIdx.x & 63;
    int grp = lane >> 4, sub = lane & 15;
    int s = rowstart[r], e = rowstart[r + 1];
    float4 a = make_float4(0.f, 0.f, 0.f, 0.f);
    for (int j = s; j < e; j += 4) {
        int idx = j + grp;
        int2 cvp = cv[(idx < e) ? idx : (e - 1)];
        float v = (idx < e) ? __int_as_float(cvp.y) : 0.f;
        const float* xp;
        if (CAT)
            xp = (cvp.x < NUM_USERS) ? (uw + (long)cvp.x * D)
                                     : (iw + (long)(cvp.x - NUM_USERS) * D);
        else
            xp = x + (long)cvp.x * D;
        float4 g = *(const float4*)(xp + sub * 4);
        a.x += v * g.x; a.y += v * g.y; a.z += v * g.z; a.w += v * g.w;
    }
    a.x += __shfl_xor(a.x, 16); a.y += __shfl_xor(a.y, 16);
    a.z += __shfl_xor(a.z, 16); a.w += __shfl_xor(a.w, 16);
    a.x += __shfl_xor(a.x, 32); a.y += __shfl_xor(a.y, 32);
    a.z += __shfl_xor(a.z, 32); a.w += __shfl_xor(a.w, 32);
    if (grp == 0) ((float4*)(y + (long)r * D))[sub] = a;
}

// ---------------------------------------------------------------------------
// Layer-3 SpMM only at the 2*BATCH batch rows, accumulated into acc.
// ---------------------------------------------------------------------------
__global__ void csr_spmm_acc(const int* __restrict__ uid, const int* __restrict__ iid,
                             const int* __restrict__ rowstart, const int2* __restrict__ cv,
                             const float* __restrict__ x, float* __restrict__ acc) {
    int b = blockIdx.x * 4 + (threadIdx.x >> 6);
    if (b >= 2 * BATCH) return;
    int lane = threadIdx.x & 63;
    int grp = lane >> 4, sub = lane & 15;
    int r = (b < BATCH) ? uid[b] : (iid[b - BATCH] + NUM_USERS);
    int s = rowstart[r], e = rowstart[r + 1];
    float4 a = make_float4(0.f, 0.f, 0.f, 0.f);
    for (int j = s; j < e; j += 4) {
        int idx = j + grp;
        int2 cvp = cv[(idx < e) ? idx : (e - 1)];
        float v = (idx < e) ? __int_as_float(cvp.y) : 0.f;
        float4 g = *(const float4*)(x + (long)cvp.x * D + sub * 4);
        a.x += v * g.x; a.y += v * g.y; a.z += v * g.z; a.w += v * g.w;
    }
    a.x += __shfl_xor(a.x, 16); a.y += __shfl_xor(a.y, 16);
    a.z += __shfl_xor(a.z, 16); a.w += __shfl_xor(a.w, 16);
    a.x += __shfl_xor(a.x, 32); a.y += __shfl_xor(a.y, 32);
    a.z += __shfl_xor(a.z, 32); a.w += __shfl_xor(a.w, 32);
    if (grp == 0) {
        float4* ap = (float4*)(acc + (long)b * D) + sub;
        float4 p = *ap;
        p.x += a.x; p.y += a.y; p.z += a.z; p.w += a.w;
        *ap = p;
    }
}

// ---------------------------------------------------------------------------
// gather_init / gather_acc at the 2*BATCH batch rows.
// ---------------------------------------------------------------------------
__global__ void gather_init(const int* __restrict__ uid, const int* __restrict__ iid,
                            const float* __restrict__ uw, const float* __restrict__ iw,
                            float* __restrict__ acc) {
    int t = blockIdx.x * blockDim.x + threadIdx.x;      // exact: 2*BATCH*16
    int b   = t >> 4;
    int sub = t & 15;
    const float* src = (b < BATCH) ? (uw + (long)uid[b] * D)
                                   : (iw + (long)iid[b - BATCH] * D);
    ((float4*)(acc + (long)b * D))[sub] = ((const float4*)src)[sub];
}

__global__ void gather_acc(const int* __restrict__ uid, const int* __restrict__ iid,
                           const float* __restrict__ x, float* __restrict__ acc) {
    int t = blockIdx.x * blockDim.x + threadIdx.x;      // exact: 2*BATCH*16
    int b   = t >> 4;
    int sub = t & 15;
    int r   = (b < BATCH) ? uid[b] : (iid[b - BATCH] + NUM_USERS);
    float4 g = *((const float4*)(x + (long)r * D) + sub);
    float4* a = (float4*)(acc + (long)b * D) + sub;
    float4 p = *a;
    p.x += g.x; p.y += g.y; p.z += g.z; p.w += g.w;
    *a = p;
}

// ---------------------------------------------------------------------------
// final: out[b] = dot(accU[b], accI[b]) / 16
// ---------------------------------------------------------------------------
__global__ void final_dot(const float* __restrict__ acc, float* __restrict__ out) {
    int t = blockIdx.x * blockDim.x + threadIdx.x;      // exact: BATCH*16
    int b   = t >> 4;
    int sub = t & 15;
    float4 u = *((const float4*)(acc + (long)b * D) + sub);
    float4 w = *((const float4*)(acc + (long)(b + BATCH) * D) + sub);
    float p = u.x * w.x + u.y * w.y + u.z * w.z + u.w * w.w;
    p += __shfl_xor(p, 1);
    p += __shfl_xor(p, 2);
    p += __shfl_xor(p, 4);
    p += __shfl_xor(p, 8);
    if (sub == 0) out[b] = p * (1.0f / 16.0f);
}

extern "C" void kernel_launch(void* const* d_in, const int* in_sizes, int n_in,
                              void* d_out, int out_size, void* d_ws, size_t ws_size,
                              hipStream_t stream) {
    const int*   user_ids = (const int*)d_in[0];
    const int*   item_ids = (const int*)d_in[1];
    const int*   adj_row  = (const int*)d_in[2];
    const int*   adj_col  = (const int*)d_in[3];
    const float* adj_val  = (const float*)d_in[4];
    const float* uw       = (const float*)d_in[5];
    const float* iw       = (const float*)d_in[6];
    float*       out      = (float*)d_out;

    // workspace bump allocator (256B aligned); total ~195.6 MB (proven OK)
    char* ws = (char*)d_ws;
    size_t off = 0;
    auto alloc = [&](size_t bytes) {
        char* p = ws + off;
        off += (bytes + 255) & ~(size_t)255;
        return p;
    };
    const size_t xbytes = (size_t)NT * D * sizeof(float);                   // 76.8 MB
    float* xA          = (float*)alloc(xbytes);
    float* xB          = (float*)alloc(xbytes);                             // also hosts entries
    float* acc         = (float*)alloc((size_t)2 * BATCH * D * sizeof(float)); // 8.4 MB
    int*   rowstart    = (int*)alloc((size_t)(NT + 1) * sizeof(int));
    int*   bcnt        = (int*)alloc((size_t)NSB * sizeof(int));
    int*   bucketstart = (int*)alloc((size_t)NSB * sizeof(int));
    char*  flags       = (char*)alloc((size_t)NT);
    int2*  cv          = (int2*)alloc((size_t)NNZ_C * sizeof(int2));        // 32 MB
    int2*  entries     = (int2*)xB;   // 293*16384*8 = 38.4 MB, dead before xB written

    // ---- bucketed CSR build ----
    hipMemsetAsync(bcnt, 0, (size_t)NSB * sizeof(int), stream);
    p1_bin<<<NCHUNK, 512, 0, stream>>>(adj_row, adj_col, adj_val, bcnt, entries);
    bucket_scan<<<1, 512, 0, stream>>>(bcnt, bucketstart, rowstart);
    p2_csr<<<NSB, SB_ROWS, 0, stream>>>(bcnt, bucketstart, entries, rowstart, cv);

    // ---- needed-row flags for layer 2 (batch rows + their neighbor cols) ----
    hipMemsetAsync(flags, 0, (size_t)NT, stream);
    mark_needed<<<(2 * BATCH) / 256, 256, 0, stream>>>(user_ids, item_ids, rowstart, cv, flags);

    // ---- layer pipeline ----
    gather_init<<<(2 * BATCH * 16) / 256, 256, 0, stream>>>(user_ids, item_ids, uw, iw, acc);

    // layer 1: reads virtual concat(uw,iw), writes xA (all rows)
    csr_spmm_k<true, false><<<(NT + 3) / 4, 256, 0, stream>>>(rowstart, cv, nullptr, uw, iw,
                                                              nullptr, xA);
    gather_acc<<<(2 * BATCH * 16) / 256, 256, 0, stream>>>(user_ids, item_ids, xA, acc);

    // layer 2: xA -> xB, only rows needed downstream (~78%)
    csr_spmm_k<false, true><<<(NT + 3) / 4, 256, 0, stream>>>(rowstart, cv, xA, nullptr, nullptr,
                                                              flags, xB);
    gather_acc<<<(2 * BATCH * 16) / 256, 256, 0, stream>>>(user_ids, item_ids, xB, acc);

    // layer 3: only the 2*BATCH batch rows, straight into acc
    csr_spmm_acc<<<(2 * BATCH + 3) / 4, 256, 0, stream>>>(user_ids, item_ids,
                                                          rowstart, cv, xB, acc);

    final_dot<<<(BATCH * 16) / 256, 256, 0, stream>>>(acc, out);
}

// Round 8
// 586.313 us; speedup vs baseline: 2.2157x; 1.0799x over previous
//
#include <hip/hip_runtime.h>

#define NUM_USERS 100000
#define NUM_ITEMS 200000
#define NT        300000        // NUM_USERS + NUM_ITEMS
#define D         64
#define NNZ_C     4000000
#define BATCH     16384

// bucketing: 1024 rows per super-bucket
#define SB_LOG    10
#define SB_ROWS   1024
#define NSB       ((NT + SB_ROWS - 1) / SB_ROWS)   // 293
#define SBCAP     16384                            // mean 13.65K, sigma~116 -> 23 sigma margin
#define CHUNK     8192
#define NCHUNK    ((NNZ_C + CHUNK - 1) / CHUNK)    // 489

// ---------------------------------------------------------------------------
// Phase 1: bin edges into NSB bucket arrays. Per-chunk LDS histogram ->
// ONE bulk global atomicAdd per (chunk,bin) -> per-edge LDS-cursor placement.
// entry.x = col | (row&1023)<<19  (col < 2^19), entry.y = bits(val)
// ---------------------------------------------------------------------------
__global__ void p1_bin(const int* __restrict__ row, const int* __restrict__ col,
                       const float* __restrict__ val, int* __restrict__ bcnt,
                       int2* __restrict__ entries) {
    __shared__ int hist[NSB];
    __shared__ int cur[NSB];
    int tid = threadIdx.x;                       // 512
    long cb = (long)blockIdx.x * CHUNK;
    int n = (int)((NNZ_C - cb < CHUNK) ? (NNZ_C - cb) : CHUNK);
    for (int i = tid; i < NSB; i += 512) hist[i] = 0;
    __syncthreads();
    for (int k = tid; k < n; k += 512)
        atomicAdd(&hist[row[cb + k] >> SB_LOG], 1);
    __syncthreads();
    for (int i = tid; i < NSB; i += 512)
        cur[i] = atomicAdd(&bcnt[i], hist[i]);   // bulk reservation
    __syncthreads();
    for (int k = tid; k < n; k += 512) {
        int r = row[cb + k];
        int b = r >> SB_LOG;
        int pos = atomicAdd(&cur[b], 1);
        if (pos < SBCAP)
            entries[(long)b * SBCAP + pos] =
                make_int2(col[cb + k] | ((r & (SB_ROWS - 1)) << 19),
                          __float_as_int(val[cb + k]));
    }
}

// ---------------------------------------------------------------------------
// Scan over NSB bucket totals (1 block). Also sets rowstart[NT] = NNZ.
// ---------------------------------------------------------------------------
__global__ void bucket_scan(const int* __restrict__ bcnt, int* __restrict__ bucketstart,
                            int* __restrict__ rowstart) {
    __shared__ int s[512];
    int tid = threadIdx.x;
    int v = (tid < NSB) ? min(bcnt[tid], SBCAP) : 0;
    int acc = v;
    s[tid] = acc; __syncthreads();
    for (int off = 1; off < 512; off <<= 1) {
        int t = (tid >= off) ? s[tid - off] : 0;
        __syncthreads();
        acc += t; s[tid] = acc; __syncthreads();
    }
    if (tid < NSB) bucketstart[tid] = acc - v;
    if (tid == 0) rowstart[NT] = s[511];
}

// ---------------------------------------------------------------------------
// Phase 2: one block per bucket. LDS histogram of 1024 rows -> LDS scan
// (produces rowstart for free) -> scatter to exact cv slots (L2-resident
// ~110KB window per block -> no write amplification).
// ---------------------------------------------------------------------------
__global__ void p2_csr(const int* __restrict__ bcnt, const int* __restrict__ bucketstart,
                       const int2* __restrict__ entries, int* __restrict__ rowstart,
                       int2* __restrict__ cv) {
    __shared__ int h[SB_ROWS];
    __shared__ int cur[SB_ROWS];
    int b = blockIdx.x, tid = threadIdx.x;       // 1024 threads
    int n = min(bcnt[b], SBCAP);
    const int2* eb = entries + (long)b * SBCAP;
    h[tid] = 0; __syncthreads();
    for (int k = tid; k < n; k += SB_ROWS)
        atomicAdd(&h[((unsigned)eb[k].x) >> 19], 1);
    __syncthreads();
    int v = h[tid];
    int acc = v;
    __syncthreads();
    for (int off = 1; off < SB_ROWS; off <<= 1) {
        int t = (tid >= off) ? h[tid - off] : 0;
        __syncthreads();
        acc += t; h[tid] = acc; __syncthreads();
    }
    int rs = bucketstart[b] + (acc - v);         // global CSR start of this row
    int grow = (b << SB_LOG) + tid;
    if (grow < NT) rowstart[grow] = rs;
    cur[tid] = rs;
    __syncthreads();
    for (int k = tid; k < n; k += SB_ROWS) {
        int2 e = eb[k];
        int rl = ((unsigned)e.x) >> 19;
        int p = atomicAdd(&cur[rl], 1);
        cv[p] = make_int2(e.x & 0x7FFFF, e.y);
    }
}

// ---------------------------------------------------------------------------
// mark rows needed from layer 2: batch rows + their edge columns.
// ---------------------------------------------------------------------------
__global__ void mark_needed(const int* __restrict__ uid, const int* __restrict__ iid,
                            const int* __restrict__ rowstart, const int2* __restrict__ cv,
                            char* __restrict__ flags) {
    int t = blockIdx.x * blockDim.x + threadIdx.x;   // exact: 2*BATCH
    int r = (t < BATCH) ? uid[t] : (iid[t - BATCH] + NUM_USERS);
    flags[r] = 1;
    int e = rowstart[r + 1];
    for (int j = rowstart[r]; j < e; ++j)
        flags[cv[j].x] = 1;
}

// ---------------------------------------------------------------------------
// CSR SpMM (gather): one 64-lane wave per row. lane = (grp = edge slot,
// sub = dim quarter); 8 edges per iteration, two independent float4
// gathers in flight per lane. Final shfl_xor(16/32) reduces edge groups.
// CAT: read virtual concat(uw,iw) as x. FILT: skip rows with flag==0.
// ---------------------------------------------------------------------------
template <bool CAT>
__device__ inline const float* xaddr(const float* __restrict__ x,
                                     const float* __restrict__ uw,
                                     const float* __restrict__ iw, int c) {
    if (CAT)
        return (c < NUM_USERS) ? (uw + (long)c * D) : (iw + (long)(c - NUM_USERS) * D);
    return x + (long)c * D;
}

template <bool CAT, bool FILT>
__global__ void csr_spmm_k(const int* __restrict__ rowstart, const int2* __restrict__ cv,
                           const float* __restrict__ x, const float* __restrict__ uw,
                           const float* __restrict__ iw, const char* __restrict__ flags,
                           float* __restrict__ y) {
    int r = blockIdx.x * 4 + (threadIdx.x >> 6);
    if (r >= NT) return;
    if (FILT && !flags[r]) return;
    int lane = threadIdx.x & 63;
    int grp = lane >> 4, sub = lane & 15;
    int s = rowstart[r], e = rowstart[r + 1];
    float4 a = make_float4(0.f, 0.f, 0.f, 0.f);
    float4 b = make_float4(0.f, 0.f, 0.f, 0.f);
    for (int j = s; j < e; j += 8) {
        int i0 = j + grp, i1 = j + 4 + grp;
        int2 p0 = cv[(i0 < e) ? i0 : (e - 1)];
        int2 p1 = cv[(i1 < e) ? i1 : (e - 1)];
        float v0 = (i0 < e) ? __int_as_float(p0.y) : 0.f;
        float v1 = (i1 < e) ? __int_as_float(p1.y) : 0.f;
        const float* xp0 = xaddr<CAT>(x, uw, iw, p0.x);
        const float* xp1 = xaddr<CAT>(x, uw, iw, p1.x);
        float4 g0 = *(const float4*)(xp0 + sub * 4);
        float4 g1 = *(const float4*)(xp1 + sub * 4);
        a.x += v0 * g0.x; a.y += v0 * g0.y; a.z += v0 * g0.z; a.w += v0 * g0.w;
        b.x += v1 * g1.x; b.y += v1 * g1.y; b.z += v1 * g1.z; b.w += v1 * g1.w;
    }
    a.x += b.x; a.y += b.y; a.z += b.z; a.w += b.w;
    a.x += __shfl_xor(a.x, 16); a.y += __shfl_xor(a.y, 16);
    a.z += __shfl_xor(a.z, 16); a.w += __shfl_xor(a.w, 16);
    a.x += __shfl_xor(a.x, 32); a.y += __shfl_xor(a.y, 32);
    a.z += __shfl_xor(a.z, 32); a.w += __shfl_xor(a.w, 32);
    if (grp == 0) ((float4*)(y + (long)r * D))[sub] = a;
}

// ---------------------------------------------------------------------------
// Layer-3 SpMM only at the 2*BATCH batch rows, accumulated into acc.
// ---------------------------------------------------------------------------
__global__ void csr_spmm_acc(const int* __restrict__ uid, const int* __restrict__ iid,
                             const int* __restrict__ rowstart, const int2* __restrict__ cv,
                             const float* __restrict__ x, float* __restrict__ acc) {
    int bidx = blockIdx.x * 4 + (threadIdx.x >> 6);
    if (bidx >= 2 * BATCH) return;
    int lane = threadIdx.x & 63;
    int grp = lane >> 4, sub = lane & 15;
    int r = (bidx < BATCH) ? uid[bidx] : (iid[bidx - BATCH] + NUM_USERS);
    int s = rowstart[r], e = rowstart[r + 1];
    float4 a = make_float4(0.f, 0.f, 0.f, 0.f);
    float4 b = make_float4(0.f, 0.f, 0.f, 0.f);
    for (int j = s; j < e; j += 8) {
        int i0 = j + grp, i1 = j + 4 + grp;
        int2 p0 = cv[(i0 < e) ? i0 : (e - 1)];
        int2 p1 = cv[(i1 < e) ? i1 : (e - 1)];
        float v0 = (i0 < e) ? __int_as_float(p0.y) : 0.f;
        float v1 = (i1 < e) ? __int_as_float(p1.y) : 0.f;
        float4 g0 = *(const float4*)(x + (long)p0.x * D + sub * 4);
        float4 g1 = *(const float4*)(x + (long)p1.x * D + sub * 4);
        a.x += v0 * g0.x; a.y += v0 * g0.y; a.z += v0 * g0.z; a.w += v0 * g0.w;
        b.x += v1 * g1.x; b.y += v1 * g1.y; b.z += v1 * g1.z; b.w += v1 * g1.w;
    }
    a.x += b.x; a.y += b.y; a.z += b.z; a.w += b.w;
    a.x += __shfl_xor(a.x, 16); a.y += __shfl_xor(a.y, 16);
    a.z += __shfl_xor(a.z, 16); a.w += __shfl_xor(a.w, 16);
    a.x += __shfl_xor(a.x, 32); a.y += __shfl_xor(a.y, 32);
    a.z += __shfl_xor(a.z, 32); a.w += __shfl_xor(a.w, 32);
    if (grp == 0) {
        float4* ap = (float4*)(acc + (long)bidx * D) + sub;
        float4 p = *ap;
        p.x += a.x; p.y += a.y; p.z += a.z; p.w += a.w;
        *ap = p;
    }
}

// ---------------------------------------------------------------------------
// gather_init / gather_acc at the 2*BATCH batch rows.
// ---------------------------------------------------------------------------
__global__ void gather_init(const int* __restrict__ uid, const int* __restrict__ iid,
                            const float* __restrict__ uw, const float* __restrict__ iw,
                            float* __restrict__ acc) {
    int t = blockIdx.x * blockDim.x + threadIdx.x;      // exact: 2*BATCH*16
    int b   = t >> 4;
    int sub = t & 15;
    const float* src = (b < BATCH) ? (uw + (long)uid[b] * D)
                                   : (iw + (long)iid[b - BATCH] * D);
    ((float4*)(acc + (long)b * D))[sub] = ((const float4*)src)[sub];
}

__global__ void gather_acc(const int* __restrict__ uid, const int* __restrict__ iid,
                           const float* __restrict__ x, float* __restrict__ acc) {
    int t = blockIdx.x * blockDim.x + threadIdx.x;      // exact: 2*BATCH*16
    int b   = t >> 4;
    int sub = t & 15;
    int r   = (b < BATCH) ? uid[b] : (iid[b - BATCH] + NUM_USERS);
    float4 g = *((const float4*)(x + (long)r * D) + sub);
    float4* a = (float4*)(acc + (long)b * D) + sub;
    float4 p = *a;
    p.x += g.x; p.y += g.y; p.z += g.z; p.w += g.w;
    *a = p;
}

// ---------------------------------------------------------------------------
// final: out[b] = dot(accU[b], accI[b]) / 16
// ---------------------------------------------------------------------------
__global__ void final_dot(const float* __restrict__ acc, float* __restrict__ out) {
    int t = blockIdx.x * blockDim.x + threadIdx.x;      // exact: BATCH*16
    int b   = t >> 4;
    int sub = t & 15;
    float4 u = *((const float4*)(acc + (long)b * D) + sub);
    float4 w = *((const float4*)(acc + (long)(b + BATCH) * D) + sub);
    float p = u.x * w.x + u.y * w.y + u.z * w.z + u.w * w.w;
    p += __shfl_xor(p, 1);
    p += __shfl_xor(p, 2);
    p += __shfl_xor(p, 4);
    p += __shfl_xor(p, 8);
    if (sub == 0) out[b] = p * (1.0f / 16.0f);
}

extern "C" void kernel_launch(void* const* d_in, const int* in_sizes, int n_in,
                              void* d_out, int out_size, void* d_ws, size_t ws_size,
                              hipStream_t stream) {
    const int*   user_ids = (const int*)d_in[0];
    const int*   item_ids = (const int*)d_in[1];
    const int*   adj_row  = (const int*)d_in[2];
    const int*   adj_col  = (const int*)d_in[3];
    const float* adj_val  = (const float*)d_in[4];
    const float* uw       = (const float*)d_in[5];
    const float* iw       = (const float*)d_in[6];
    float*       out      = (float*)d_out;

    // workspace bump allocator (256B aligned); total ~195.6 MB (proven OK)
    char* ws = (char*)d_ws;
    size_t off = 0;
    auto alloc = [&](size_t bytes) {
        char* p = ws + off;
        off += (bytes + 255) & ~(size_t)255;
        return p;
    };
    const size_t xbytes = (size_t)NT * D * sizeof(float);                   // 76.8 MB
    float* xA          = (float*)alloc(xbytes);
    float* xB          = (float*)alloc(xbytes);                             // also hosts entries
    float* acc         = (float*)alloc((size_t)2 * BATCH * D * sizeof(float)); // 8.4 MB
    int*   rowstart    = (int*)alloc((size_t)(NT + 1) * sizeof(int));
    int*   bcnt        = (int*)alloc((size_t)NSB * sizeof(int));
    int*   bucketstart = (int*)alloc((size_t)NSB * sizeof(int));
    char*  flags       = (char*)alloc((size_t)NT);
    int2*  cv          = (int2*)alloc((size_t)NNZ_C * sizeof(int2));        // 32 MB
    int2*  entries     = (int2*)xB;   // 293*16384*8 = 38.4 MB, dead before xB written

    // ---- bucketed CSR build ----
    hipMemsetAsync(bcnt, 0, (size_t)NSB * sizeof(int), stream);
    p1_bin<<<NCHUNK, 512, 0, stream>>>(adj_row, adj_col, adj_val, bcnt, entries);
    bucket_scan<<<1, 512, 0, stream>>>(bcnt, bucketstart, rowstart);
    p2_csr<<<NSB, SB_ROWS, 0, stream>>>(bcnt, bucketstart, entries, rowstart, cv);

    // ---- needed-row flags for layer 2 (batch rows + their neighbor cols) ----
    hipMemsetAsync(flags, 0, (size_t)NT, stream);
    mark_needed<<<(2 * BATCH) / 256, 256, 0, stream>>>(user_ids, item_ids, rowstart, cv, flags);

    // ---- layer pipeline ----
    gather_init<<<(2 * BATCH * 16) / 256, 256, 0, stream>>>(user_ids, item_ids, uw, iw, acc);

    // layer 1: reads virtual concat(uw,iw), writes xA (all rows)
    csr_spmm_k<true, false><<<(NT + 3) / 4, 256, 0, stream>>>(rowstart, cv, nullptr, uw, iw,
                                                              nullptr, xA);
    gather_acc<<<(2 * BATCH * 16) / 256, 256, 0, stream>>>(user_ids, item_ids, xA, acc);

    // layer 2: xA -> xB, only rows needed downstream (~78%)
    csr_spmm_k<false, true><<<(NT + 3) / 4, 256, 0, stream>>>(rowstart, cv, xA, nullptr, nullptr,
                                                              flags, xB);
    gather_acc<<<(2 * BATCH * 16) / 256, 256, 0, stream>>>(user_ids, item_ids, xB, acc);

    // layer 3: only the 2*BATCH batch rows, straight into acc
    csr_spmm_acc<<<(2 * BATCH + 3) / 4, 256, 0, stream>>>(user_ids, item_ids,
                                                          rowstart, cv, xB, acc);

    final_dot<<<(BATCH * 16) / 256, 256, 0, stream>>>(acc, out);
}

// Round 9
// 511.642 us; speedup vs baseline: 2.5390x; 1.1459x over previous
//
#include <hip/hip_runtime.h>
#include <hip/hip_fp16.h>

#define NUM_USERS 100000
#define NUM_ITEMS 200000
#define NT        300000        // NUM_USERS + NUM_ITEMS
#define D         64
#define NNZ_C     4000000
#define BATCH     16384

// bucketing: 1024 rows per super-bucket
#define SB_LOG    10
#define SB_ROWS   1024
#define NSB       ((NT + SB_ROWS - 1) / SB_ROWS)   // 293
#define SBCAP     16384                            // mean 13.65K/bucket, huge margin
#define CHUNK     8192
#define NCHUNK    ((NNZ_C + CHUNK - 1) / CHUNK)    // 489

// ---------------------------------------------------------------------------
// fp16 helpers: x stored as ushort (half); 8 halves = uint4 = 16B per lane.
// ---------------------------------------------------------------------------
__device__ inline void fma8(float4& a, float4& b, float v, uint4 g) {
    const __half2* h = (const __half2*)&g;
    float2 f0 = __half22float2(h[0]); a.x += v * f0.x; a.y += v * f0.y;
    float2 f1 = __half22float2(h[1]); a.z += v * f1.x; a.w += v * f1.y;
    float2 f2 = __half22float2(h[2]); b.x += v * f2.x; b.y += v * f2.y;
    float2 f3 = __half22float2(h[3]); b.z += v * f3.x; b.w += v * f3.y;
}

__device__ inline unsigned pack2(float x, float y) {
    __half2 h = __floats2half2_rn(x, y);
    return *(unsigned*)&h;
}

// ---------------------------------------------------------------------------
// Phase 1: bin edges into NSB bucket arrays (bulk-reserved LDS cursors).
// entry.x = col | (row&1023)<<19, entry.y = bits(val)
// ---------------------------------------------------------------------------
__global__ void p1_bin(const int* __restrict__ row, const int* __restrict__ col,
                       const float* __restrict__ val, int* __restrict__ bcnt,
                       int2* __restrict__ entries) {
    __shared__ int hist[NSB];
    __shared__ int cur[NSB];
    int tid = threadIdx.x;                       // 512
    long cb = (long)blockIdx.x * CHUNK;
    int n = (int)((NNZ_C - cb < CHUNK) ? (NNZ_C - cb) : CHUNK);
    for (int i = tid; i < NSB; i += 512) hist[i] = 0;
    __syncthreads();
    for (int k = tid; k < n; k += 512)
        atomicAdd(&hist[row[cb + k] >> SB_LOG], 1);
    __syncthreads();
    for (int i = tid; i < NSB; i += 512)
        cur[i] = atomicAdd(&bcnt[i], hist[i]);   // bulk reservation
    __syncthreads();
    for (int k = tid; k < n; k += 512) {
        int r = row[cb + k];
        int b = r >> SB_LOG;
        int pos = atomicAdd(&cur[b], 1);
        if (pos < SBCAP)
            entries[(long)b * SBCAP + pos] =
                make_int2(col[cb + k] | ((r & (SB_ROWS - 1)) << 19),
                          __float_as_int(val[cb + k]));
    }
}

__global__ void bucket_scan(const int* __restrict__ bcnt, int* __restrict__ bucketstart,
                            int* __restrict__ rowstart) {
    __shared__ int s[512];
    int tid = threadIdx.x;
    int v = (tid < NSB) ? min(bcnt[tid], SBCAP) : 0;
    int acc = v;
    s[tid] = acc; __syncthreads();
    for (int off = 1; off < 512; off <<= 1) {
        int t = (tid >= off) ? s[tid - off] : 0;
        __syncthreads();
        acc += t; s[tid] = acc; __syncthreads();
    }
    if (tid < NSB) bucketstart[tid] = acc - v;
    if (tid == 0) rowstart[NT] = s[511];
}

// ---------------------------------------------------------------------------
// Phase 2: one block per bucket -> LDS histogram+scan -> exact cv scatter.
// ---------------------------------------------------------------------------
__global__ void p2_csr(const int* __restrict__ bcnt, const int* __restrict__ bucketstart,
                       const int2* __restrict__ entries, int* __restrict__ rowstart,
                       int2* __restrict__ cv) {
    __shared__ int h[SB_ROWS];
    __shared__ int cur[SB_ROWS];
    int b = blockIdx.x, tid = threadIdx.x;       // 1024 threads
    int n = min(bcnt[b], SBCAP);
    const int2* eb = entries + (long)b * SBCAP;
    h[tid] = 0; __syncthreads();
    for (int k = tid; k < n; k += SB_ROWS)
        atomicAdd(&h[((unsigned)eb[k].x) >> 19], 1);
    __syncthreads();
    int v = h[tid];
    int acc = v;
    __syncthreads();
    for (int off = 1; off < SB_ROWS; off <<= 1) {
        int t = (tid >= off) ? h[tid - off] : 0;
        __syncthreads();
        acc += t; h[tid] = acc; __syncthreads();
    }
    int rs = bucketstart[b] + (acc - v);
    int grow = (b << SB_LOG) + tid;
    if (grow < NT) rowstart[grow] = rs;
    cur[tid] = rs;
    __syncthreads();
    for (int k = tid; k < n; k += SB_ROWS) {
        int2 e = eb[k];
        int rl = ((unsigned)e.x) >> 19;
        int p = atomicAdd(&cur[rl], 1);
        cv[p] = make_int2(e.x & 0x7FFFF, e.y);
    }
}

// ---------------------------------------------------------------------------
// mark rows needed from layer 2: batch rows + their edge columns.
// ---------------------------------------------------------------------------
__global__ void mark_needed(const int* __restrict__ uid, const int* __restrict__ iid,
                            const int* __restrict__ rowstart, const int2* __restrict__ cv,
                            char* __restrict__ flags) {
    int t = blockIdx.x * blockDim.x + threadIdx.x;   // exact: 2*BATCH
    int r = (t < BATCH) ? uid[t] : (iid[t - BATCH] + NUM_USERS);
    flags[r] = 1;
    int e = rowstart[r + 1];
    for (int j = rowstart[r]; j < e; ++j)
        flags[cv[j].x] = 1;
}

// ---------------------------------------------------------------------------
// init_x0: fp16 copy of concat(uw, iw). t covers 8 dims (16B out).
// ---------------------------------------------------------------------------
__global__ void init_x0(const float* __restrict__ uw, const float* __restrict__ iw,
                        unsigned short* __restrict__ x0) {
    int t = blockIdx.x * blockDim.x + threadIdx.x;   // exact: NT*8
    int r = t >> 3, sub = t & 7;
    const float* src = (r < NUM_USERS) ? (uw + (long)r * D)
                                       : (iw + (long)(r - NUM_USERS) * D);
    float4 f0 = ((const float4*)src)[sub * 2];
    float4 f1 = ((const float4*)src)[sub * 2 + 1];
    uint4 o;
    o.x = pack2(f0.x, f0.y); o.y = pack2(f0.z, f0.w);
    o.z = pack2(f1.x, f1.y); o.w = pack2(f1.z, f1.w);
    ((uint4*)(x0 + (long)r * D))[sub] = o;
}

// ---------------------------------------------------------------------------
// fp16 CSR SpMM: one 64-lane wave per row; grp = lane>>3 (8 edge slots),
// sub = lane&7 (16B = 8 dims). 16 edges per iter (unroll 2). Reduction:
// shfl_xor 8/16/32. grp 0 stores the fp16 row (uint4 per lane).
// FILT: skip rows with flag==0.
// ---------------------------------------------------------------------------
template <bool FILT>
__global__ void csr_spmm_h(const int* __restrict__ rowstart, const int2* __restrict__ cv,
                           const unsigned short* __restrict__ x,
                           const char* __restrict__ flags,
                           unsigned short* __restrict__ y) {
    int r = blockIdx.x * 4 + (threadIdx.x >> 6);
    if (r >= NT) return;
    if (FILT && !flags[r]) return;
    int lane = threadIdx.x & 63;
    int grp = lane >> 3, sub = lane & 7;
    int s = rowstart[r], e = rowstart[r + 1];
    float4 a0 = make_float4(0.f, 0.f, 0.f, 0.f), a1 = a0;
    float4 b0 = a0, b1 = a0;
    for (int j = s; j < e; j += 16) {
        int i0 = j + grp, i1 = j + 8 + grp;
        int2 p0 = cv[(i0 < e) ? i0 : (e - 1)];
        int2 p1 = cv[(i1 < e) ? i1 : (e - 1)];
        float v0 = (i0 < e) ? __int_as_float(p0.y) : 0.f;
        float v1 = (i1 < e) ? __int_as_float(p1.y) : 0.f;
        uint4 g0 = *(const uint4*)(x + (long)p0.x * D + sub * 8);
        uint4 g1 = *(const uint4*)(x + (long)p1.x * D + sub * 8);
        fma8(a0, a1, v0, g0);
        fma8(b0, b1, v1, g1);
    }
    a0.x += b0.x; a0.y += b0.y; a0.z += b0.z; a0.w += b0.w;
    a1.x += b1.x; a1.y += b1.y; a1.z += b1.z; a1.w += b1.w;
    #pragma unroll
    for (int off = 8; off <= 32; off <<= 1) {
        a0.x += __shfl_xor(a0.x, off); a0.y += __shfl_xor(a0.y, off);
        a0.z += __shfl_xor(a0.z, off); a0.w += __shfl_xor(a0.w, off);
        a1.x += __shfl_xor(a1.x, off); a1.y += __shfl_xor(a1.y, off);
        a1.z += __shfl_xor(a1.z, off); a1.w += __shfl_xor(a1.w, off);
    }
    if (grp == 0) {
        uint4 o;
        o.x = pack2(a0.x, a0.y); o.y = pack2(a0.z, a0.w);
        o.z = pack2(a1.x, a1.y); o.w = pack2(a1.z, a1.w);
        ((uint4*)(y + (long)r * D))[sub] = o;
    }
}

// ---------------------------------------------------------------------------
// Layer-3 SpMM at the 2*BATCH batch rows, accumulated into fp32 acc.
// ---------------------------------------------------------------------------
__global__ void csr_spmm_acc_h(const int* __restrict__ uid, const int* __restrict__ iid,
                               const int* __restrict__ rowstart, const int2* __restrict__ cv,
                               const unsigned short* __restrict__ x,
                               float* __restrict__ acc) {
    int bidx = blockIdx.x * 4 + (threadIdx.x >> 6);
    if (bidx >= 2 * BATCH) return;
    int lane = threadIdx.x & 63;
    int grp = lane >> 3, sub = lane & 7;
    int r = (bidx < BATCH) ? uid[bidx] : (iid[bidx - BATCH] + NUM_USERS);
    int s = rowstart[r], e = rowstart[r + 1];
    float4 a0 = make_float4(0.f, 0.f, 0.f, 0.f), a1 = a0;
    float4 b0 = a0, b1 = a0;
    for (int j = s; j < e; j += 16) {
        int i0 = j + grp, i1 = j + 8 + grp;
        int2 p0 = cv[(i0 < e) ? i0 : (e - 1)];
        int2 p1 = cv[(i1 < e) ? i1 : (e - 1)];
        float v0 = (i0 < e) ? __int_as_float(p0.y) : 0.f;
        float v1 = (i1 < e) ? __int_as_float(p1.y) : 0.f;
        uint4 g0 = *(const uint4*)(x + (long)p0.x * D + sub * 8);
        uint4 g1 = *(const uint4*)(x + (long)p1.x * D + sub * 8);
        fma8(a0, a1, v0, g0);
        fma8(b0, b1, v1, g1);
    }
    a0.x += b0.x; a0.y += b0.y; a0.z += b0.z; a0.w += b0.w;
    a1.x += b1.x; a1.y += b1.y; a1.z += b1.z; a1.w += b1.w;
    #pragma unroll
    for (int off = 8; off <= 32; off <<= 1) {
        a0.x += __shfl_xor(a0.x, off); a0.y += __shfl_xor(a0.y, off);
        a0.z += __shfl_xor(a0.z, off); a0.w += __shfl_xor(a0.w, off);
        a1.x += __shfl_xor(a1.x, off); a1.y += __shfl_xor(a1.y, off);
        a1.z += __shfl_xor(a1.z, off); a1.w += __shfl_xor(a1.w, off);
    }
    if (grp == 0) {
        float4* ap = (float4*)(acc + (long)bidx * D) + sub * 2;
        float4 q0 = ap[0], q1 = ap[1];
        q0.x += a0.x; q0.y += a0.y; q0.z += a0.z; q0.w += a0.w;
        q1.x += a1.x; q1.y += a1.y; q1.z += a1.z; q1.w += a1.w;
        ap[0] = q0; ap[1] = q1;
    }
}

// ---------------------------------------------------------------------------
// gather_init (fp32 weights) / gather_acc_h (fp16 x) at batch rows.
// ---------------------------------------------------------------------------
__global__ void gather_init(const int* __restrict__ uid, const int* __restrict__ iid,
                            const float* __restrict__ uw, const float* __restrict__ iw,
                            float* __restrict__ acc) {
    int t = blockIdx.x * blockDim.x + threadIdx.x;      // exact: 2*BATCH*16
    int b   = t >> 4;
    int sub = t & 15;
    const float* src = (b < BATCH) ? (uw + (long)uid[b] * D)
                                   : (iw + (long)iid[b - BATCH] * D);
    ((float4*)(acc + (long)b * D))[sub] = ((const float4*)src)[sub];
}

__global__ void gather_acc_h(const int* __restrict__ uid, const int* __restrict__ iid,
                             const unsigned short* __restrict__ x, float* __restrict__ acc) {
    int t = blockIdx.x * blockDim.x + threadIdx.x;      // exact: 2*BATCH*8
    int b   = t >> 3;
    int sub = t & 7;
    int r   = (b < BATCH) ? uid[b] : (iid[b - BATCH] + NUM_USERS);
    uint4 g = ((const uint4*)(x + (long)r * D))[sub];
    const __half2* h = (const __half2*)&g;
    float4* ap = (float4*)(acc + (long)b * D) + sub * 2;
    float4 q0 = ap[0], q1 = ap[1];
    float2 f0 = __half22float2(h[0]); q0.x += f0.x; q0.y += f0.y;
    float2 f1 = __half22float2(h[1]); q0.z += f1.x; q0.w += f1.y;
    float2 f2 = __half22float2(h[2]); q1.x += f2.x; q1.y += f2.y;
    float2 f3 = __half22float2(h[3]); q1.z += f3.x; q1.w += f3.y;
    ap[0] = q0; ap[1] = q1;
}

// ---------------------------------------------------------------------------
// final: out[b] = dot(accU[b], accI[b]) / 16
// ---------------------------------------------------------------------------
__global__ void final_dot(const float* __restrict__ acc, float* __restrict__ out) {
    int t = blockIdx.x * blockDim.x + threadIdx.x;      // exact: BATCH*16
    int b   = t >> 4;
    int sub = t & 15;
    float4 u = *((const float4*)(acc + (long)b * D) + sub);
    float4 w = *((const float4*)(acc + (long)(b + BATCH) * D) + sub);
    float p = u.x * w.x + u.y * w.y + u.z * w.z + u.w * w.w;
    p += __shfl_xor(p, 1);
    p += __shfl_xor(p, 2);
    p += __shfl_xor(p, 4);
    p += __shfl_xor(p, 8);
    if (sub == 0) out[b] = p * (1.0f / 16.0f);
}

extern "C" void kernel_launch(void* const* d_in, const int* in_sizes, int n_in,
                              void* d_out, int out_size, void* d_ws, size_t ws_size,
                              hipStream_t stream) {
    const int*   user_ids = (const int*)d_in[0];
    const int*   item_ids = (const int*)d_in[1];
    const int*   adj_row  = (const int*)d_in[2];
    const int*   adj_col  = (const int*)d_in[3];
    const float* adj_val  = (const float*)d_in[4];
    const float* uw       = (const float*)d_in[5];
    const float* iw       = (const float*)d_in[6];
    float*       out      = (float*)d_out;

    // workspace bump allocator (256B aligned); total ~119 MB (well under proven 195MB)
    char* ws = (char*)d_ws;
    size_t off = 0;
    auto alloc = [&](size_t bytes) {
        char* p = ws + off;
        off += (bytes + 255) & ~(size_t)255;
        return p;
    };
    const size_t xhbytes = (size_t)NT * D * sizeof(unsigned short);         // 38.4 MB
    const size_t ebytes  = (size_t)NSB * SBCAP * sizeof(int2);              // 38.4 MB
    unsigned short* x0h = (unsigned short*)alloc(xhbytes);
    unsigned short* xAh = (unsigned short*)alloc(xhbytes);
    unsigned short* xBh = (unsigned short*)alloc(ebytes > xhbytes ? ebytes : xhbytes);
    float* acc          = (float*)alloc((size_t)2 * BATCH * D * sizeof(float)); // 8.4 MB
    int*   rowstart     = (int*)alloc((size_t)(NT + 1) * sizeof(int));
    int*   bcnt         = (int*)alloc((size_t)NSB * sizeof(int));
    int*   bucketstart  = (int*)alloc((size_t)NSB * sizeof(int));
    char*  flags        = (char*)alloc((size_t)NT);
    int2*  cv           = (int2*)alloc((size_t)NNZ_C * sizeof(int2));       // 32 MB
    int2*  entries      = (int2*)xBh;   // dead before xBh first written (layer 2)

    // ---- bucketed CSR build ----
    hipMemsetAsync(bcnt, 0, (size_t)NSB * sizeof(int), stream);
    p1_bin<<<NCHUNK, 512, 0, stream>>>(adj_row, adj_col, adj_val, bcnt, entries);
    bucket_scan<<<1, 512, 0, stream>>>(bcnt, bucketstart, rowstart);
    p2_csr<<<NSB, SB_ROWS, 0, stream>>>(bcnt, bucketstart, entries, rowstart, cv);

    // ---- needed-row flags for layer 2 ----
    hipMemsetAsync(flags, 0, (size_t)NT, stream);
    mark_needed<<<(2 * BATCH) / 256, 256, 0, stream>>>(user_ids, item_ids, rowstart, cv, flags);

    // ---- layer pipeline (x stored fp16, accumulation fp32) ----
    init_x0<<<(NT * 8) / 256, 256, 0, stream>>>(uw, iw, x0h);
    gather_init<<<(2 * BATCH * 16) / 256, 256, 0, stream>>>(user_ids, item_ids, uw, iw, acc);

    // layer 1: x0h -> xAh (all rows)
    csr_spmm_h<false><<<(NT + 3) / 4, 256, 0, stream>>>(rowstart, cv, x0h, nullptr, xAh);
    gather_acc_h<<<(2 * BATCH * 8) / 256, 256, 0, stream>>>(user_ids, item_ids, xAh, acc);

    // layer 2: xAh -> xBh, only rows needed downstream (~78%)
    csr_spmm_h<true><<<(NT + 3) / 4, 256, 0, stream>>>(rowstart, cv, xAh, flags, xBh);
    gather_acc_h<<<(2 * BATCH * 8) / 256, 256, 0, stream>>>(user_ids, item_ids, xBh, acc);

    // layer 3: only the 2*BATCH batch rows, straight into fp32 acc
    csr_spmm_acc_h<<<(2 * BATCH + 3) / 4, 256, 0, stream>>>(user_ids, item_ids,
                                                            rowstart, cv, xBh, acc);

    final_dot<<<(BATCH * 16) / 256, 256, 0, stream>>>(acc, out);
}

// Round 11
// 510.369 us; speedup vs baseline: 2.5454x; 1.0025x over previous
//
#include <hip/hip_runtime.h>
#include <hip/hip_fp16.h>

#define NUM_USERS 100000
#define NUM_ITEMS 200000
#define NT        300000        // NUM_USERS + NUM_ITEMS
#define D         64
#define NNZ_C     4000000
#define BATCH     16384

// bucketing: 1024 rows per super-bucket
#define SB_LOG    10
#define SB_ROWS   1024
#define NSB       ((NT + SB_ROWS - 1) / SB_ROWS)   // 293
#define SBCAP     16384                            // raw edges per bucket cap (mean 13.65K)
#define BSTRIDE   24576                            // padded cv entries per bucket (fixed stride)
#define CHUNK     8192
#define NCHUNK    ((NNZ_C + CHUNK - 1) / CHUNK)    // 489

// ---------------------------------------------------------------------------
// fp16 helpers
// ---------------------------------------------------------------------------
__device__ inline unsigned pack2(float x, float y) {
    __half2 h = __floats2half2_rn(x, y);
    return *(unsigned*)&h;
}

// a/b accumulate 8 dims from uint4 of 8 halves, scaled by fp32 v, via
// v_fma_mix_f32 (inline f16->f32 convert inside the FMA; fp32 accumulate).
__device__ inline void fma_mix8(float4& a, float4& b, uint4 g, float v) {
    asm("v_fma_mix_f32 %0, %2, %3, %0 op_sel:[0,0,0] op_sel_hi:[1,0,0]\n\t"
        "v_fma_mix_f32 %1, %2, %3, %1 op_sel:[1,0,0] op_sel_hi:[1,0,0]"
        : "+v"(a.x), "+v"(a.y) : "v"(g.x), "v"(v));
    asm("v_fma_mix_f32 %0, %2, %3, %0 op_sel:[0,0,0] op_sel_hi:[1,0,0]\n\t"
        "v_fma_mix_f32 %1, %2, %3, %1 op_sel:[1,0,0] op_sel_hi:[1,0,0]"
        : "+v"(a.z), "+v"(a.w) : "v"(g.y), "v"(v));
    asm("v_fma_mix_f32 %0, %2, %3, %0 op_sel:[0,0,0] op_sel_hi:[1,0,0]\n\t"
        "v_fma_mix_f32 %1, %2, %3, %1 op_sel:[1,0,0] op_sel_hi:[1,0,0]"
        : "+v"(b.x), "+v"(b.y) : "v"(g.z), "v"(v));
    asm("v_fma_mix_f32 %0, %2, %3, %0 op_sel:[0,0,0] op_sel_hi:[1,0,0]\n\t"
        "v_fma_mix_f32 %1, %2, %3, %1 op_sel:[1,0,0] op_sel_hi:[1,0,0]"
        : "+v"(b.z), "+v"(b.w) : "v"(g.w), "v"(v));
}

// ---------------------------------------------------------------------------
// Phase 1: bin edges into NSB bucket arrays (bulk-reserved LDS cursors).
// entry.x = col | (row&1023)<<19, entry.y = bits(val)
// ---------------------------------------------------------------------------
__global__ void p1_bin(const int* __restrict__ row, const int* __restrict__ col,
                       const float* __restrict__ val, int* __restrict__ bcnt,
                       int2* __restrict__ entries) {
    __shared__ int hist[NSB];
    __shared__ int cur[NSB];
    int tid = threadIdx.x;                       // 512
    long cb = (long)blockIdx.x * CHUNK;
    int n = (int)((NNZ_C - cb < CHUNK) ? (NNZ_C - cb) : CHUNK);
    for (int i = tid; i < NSB; i += 512) hist[i] = 0;
    __syncthreads();
    for (int k = tid; k < n; k += 512)
        atomicAdd(&hist[row[cb + k] >> SB_LOG], 1);
    __syncthreads();
    for (int i = tid; i < NSB; i += 512)
        cur[i] = atomicAdd(&bcnt[i], hist[i]);   // bulk reservation
    __syncthreads();
    for (int k = tid; k < n; k += 512) {
        int r = row[cb + k];
        int b = r >> SB_LOG;
        int pos = atomicAdd(&cur[b], 1);
        if (pos < SBCAP)
            entries[(long)b * SBCAP + pos] =
                make_int2(col[cb + k] | ((r & (SB_ROWS - 1)) << 19),
                          __float_as_int(val[cb + k]));
    }
}

// ---------------------------------------------------------------------------
// Phase 2: one block per bucket -> LDS histogram -> pad per-row counts to
// multiple of 16 -> LDS scan (rowstart/rowend for free; fixed bucket stride
// so no cross-bucket scan needed) -> exact cv scatter -> zero pad slots.
// ---------------------------------------------------------------------------
__global__ void p2_csr(const int* __restrict__ bcnt, const int2* __restrict__ entries,
                       int* __restrict__ rowstart, int* __restrict__ rowend,
                       int2* __restrict__ cv) {
    __shared__ int h[SB_ROWS];
    __shared__ int cur[SB_ROWS];
    int b = blockIdx.x, tid = threadIdx.x;       // 1024 threads
    int n = min(bcnt[b], SBCAP);
    const int2* eb = entries + (long)b * SBCAP;
    h[tid] = 0; __syncthreads();
    for (int k = tid; k < n; k += SB_ROWS)
        atomicAdd(&h[((unsigned)eb[k].x) >> 19], 1);
    __syncthreads();
    int raw = h[tid];
    int pad = (raw + 15) & ~15;
    h[tid] = pad;
    int acc = pad;
    __syncthreads();
    for (int off = 1; off < SB_ROWS; off <<= 1) {
        int t = (tid >= off) ? h[tid - off] : 0;
        __syncthreads();
        acc += t; h[tid] = acc; __syncthreads();
    }
    int rs = b * BSTRIDE + (acc - pad);
    int grow = (b << SB_LOG) + tid;
    if (grow < NT) { rowstart[grow] = rs; rowend[grow] = rs + pad; }
    cur[tid] = rs;
    __syncthreads();
    for (int k = tid; k < n; k += SB_ROWS) {
        int2 e = eb[k];
        int rl = ((unsigned)e.x) >> 19;
        int p = atomicAdd(&cur[rl], 1);
        cv[p] = make_int2(e.x & 0x7FFFF, e.y);
    }
    // pad fill: disjoint slots [rs+raw, rs+pad), no sync needed
    for (int p = rs + raw; p < rs + pad; ++p)
        cv[p] = make_int2(0, 0);
}

// ---------------------------------------------------------------------------
// mark rows needed from layer 2: batch rows + their edge columns.
// (pads mark row 0 spuriously -- harmless)
// ---------------------------------------------------------------------------
__global__ void mark_needed(const int* __restrict__ uid, const int* __restrict__ iid,
                            const int* __restrict__ rowstart, const int* __restrict__ rowend,
                            const int2* __restrict__ cv, char* __restrict__ flags) {
    int t = blockIdx.x * blockDim.x + threadIdx.x;   // exact: 2*BATCH
    int r = (t < BATCH) ? uid[t] : (iid[t - BATCH] + NUM_USERS);
    flags[r] = 1;
    int e = rowend[r];
    for (int j = rowstart[r]; j < e; ++j)
        flags[cv[j].x] = 1;
}

// ---------------------------------------------------------------------------
// init_x0: fp16 copy of concat(uw, iw). t covers 8 dims (16B out).
// ---------------------------------------------------------------------------
__global__ void init_x0(const float* __restrict__ uw, const float* __restrict__ iw,
                        unsigned short* __restrict__ x0) {
    int t = blockIdx.x * blockDim.x + threadIdx.x;   // exact: NT*8
    int r = t >> 3, sub = t & 7;
    const float* src = (r < NUM_USERS) ? (uw + (long)r * D)
                                       : (iw + (long)(r - NUM_USERS) * D);
    float4 f0 = ((const float4*)src)[sub * 2];
    float4 f1 = ((const float4*)src)[sub * 2 + 1];
    uint4 o;
    o.x = pack2(f0.x, f0.y); o.y = pack2(f0.z, f0.w);
    o.z = pack2(f1.x, f1.y); o.w = pack2(f1.z, f1.w);
    ((uint4*)(x0 + (long)r * D))[sub] = o;
}

// ---------------------------------------------------------------------------
// fp16 CSR SpMM, guard-free (rows padded to multiple of 16 edges):
// one 64-lane wave per row; grp = lane>>3 (8 edge slots), sub = lane&7
// (16B = 8 dims). 16 edges/iter, two independent gathers in flight.
// FILT: skip rows with flag==0.
// ---------------------------------------------------------------------------
template <bool FILT>
__global__ void csr_spmm_h(const int* __restrict__ rowstart, const int* __restrict__ rowend,
                           const int2* __restrict__ cv, const unsigned short* __restrict__ x,
                           const char* __restrict__ flags, unsigned short* __restrict__ y) {
    int r = blockIdx.x * 4 + (threadIdx.x >> 6);
    if (r >= NT) return;
    if (FILT && !flags[r]) return;
    int lane = threadIdx.x & 63;
    int grp = lane >> 3, sub = lane & 7;
    int s = rowstart[r], e = rowend[r];
    const unsigned short* xs = x + sub * 8;
    float4 a0 = make_float4(0.f, 0.f, 0.f, 0.f), a1 = a0, b0 = a0, b1 = a0;
    for (int j = s + grp; j < e; j += 16) {
        int2 p0 = cv[j];
        int2 p1 = cv[j + 8];
        uint4 g0 = *(const uint4*)(xs + (long)p0.x * D);
        uint4 g1 = *(const uint4*)(xs + (long)p1.x * D);
        fma_mix8(a0, a1, g0, __int_as_float(p0.y));
        fma_mix8(b0, b1, g1, __int_as_float(p1.y));
    }
    a0.x += b0.x; a0.y += b0.y; a0.z += b0.z; a0.w += b0.w;
    a1.x += b1.x; a1.y += b1.y; a1.z += b1.z; a1.w += b1.w;
    #pragma unroll
    for (int off = 8; off <= 32; off <<= 1) {
        a0.x += __shfl_xor(a0.x, off); a0.y += __shfl_xor(a0.y, off);
        a0.z += __shfl_xor(a0.z, off); a0.w += __shfl_xor(a0.w, off);
        a1.x += __shfl_xor(a1.x, off); a1.y += __shfl_xor(a1.y, off);
        a1.z += __shfl_xor(a1.z, off); a1.w += __shfl_xor(a1.w, off);
    }
    if (grp == 0) {
        uint4 o;
        o.x = pack2(a0.x, a0.y); o.y = pack2(a0.z, a0.w);
        o.z = pack2(a1.x, a1.y); o.w = pack2(a1.z, a1.w);
        ((uint4*)(y + (long)r * D))[sub] = o;
    }
}

// ---------------------------------------------------------------------------
// Layer-3 SpMM at the 2*BATCH batch rows, accumulated into fp32 acc.
// ---------------------------------------------------------------------------
__global__ void csr_spmm_acc_h(const int* __restrict__ uid, const int* __restrict__ iid,
                               const int* __restrict__ rowstart, const int* __restrict__ rowend,
                               const int2* __restrict__ cv,
                               const unsigned short* __restrict__ x,
                               float* __restrict__ acc) {
    int bidx = blockIdx.x * 4 + (threadIdx.x >> 6);
    if (bidx >= 2 * BATCH) return;
    int lane = threadIdx.x & 63;
    int grp = lane >> 3, sub = lane & 7;
    int r = (bidx < BATCH) ? uid[bidx] : (iid[bidx - BATCH] + NUM_USERS);
    int s = rowstart[r], e = rowend[r];
    const unsigned short* xs = x + sub * 8;
    float4 a0 = make_float4(0.f, 0.f, 0.f, 0.f), a1 = a0, b0 = a0, b1 = a0;
    for (int j = s + grp; j < e; j += 16) {
        int2 p0 = cv[j];
        int2 p1 = cv[j + 8];
        uint4 g0 = *(const uint4*)(xs + (long)p0.x * D);
        uint4 g1 = *(const uint4*)(xs + (long)p1.x * D);
        fma_mix8(a0, a1, g0, __int_as_float(p0.y));
        fma_mix8(b0, b1, g1, __int_as_float(p1.y));
    }
    a0.x += b0.x; a0.y += b0.y; a0.z += b0.z; a0.w += b0.w;
    a1.x += b1.x; a1.y += b1.y; a1.z += b1.z; a1.w += b1.w;
    #pragma unroll
    for (int off = 8; off <= 32; off <<= 1) {
        a0.x += __shfl_xor(a0.x, off); a0.y += __shfl_xor(a0.y, off);
        a0.z += __shfl_xor(a0.z, off); a0.w += __shfl_xor(a0.w, off);
        a1.x += __shfl_xor(a1.x, off); a1.y += __shfl_xor(a1.y, off);
        a1.z += __shfl_xor(a1.z, off); a1.w += __shfl_xor(a1.w, off);
    }
    if (grp == 0) {
        float4* ap = (float4*)(acc + (long)bidx * D) + sub * 2;
        float4 q0 = ap[0], q1 = ap[1];
        q0.x += a0.x; q0.y += a0.y; q0.z += a0.z; q0.w += a0.w;
        q1.x += a1.x; q1.y += a1.y; q1.z += a1.z; q1.w += a1.w;
        ap[0] = q0; ap[1] = q1;
    }
}

// ---------------------------------------------------------------------------
// gather_init (fp32 weights) / gather_acc_h (fp16 x) at batch rows.
// ---------------------------------------------------------------------------
__global__ void gather_init(const int* __restrict__ uid, const int* __restrict__ iid,
                            const float* __restrict__ uw, const float* __restrict__ iw,
                            float* __restrict__ acc) {
    int t = blockIdx.x * blockDim.x + threadIdx.x;      // exact: 2*BATCH*16
    int b   = t >> 4;
    int sub = t & 15;
    const float* src = (b < BATCH) ? (uw + (long)uid[b] * D)
                                   : (iw + (long)iid[b - BATCH] * D);
    ((float4*)(acc + (long)b * D))[sub] = ((const float4*)src)[sub];
}

__global__ void gather_acc_h(const int* __restrict__ uid, const int* __restrict__ iid,
                             const unsigned short* __restrict__ x, float* __restrict__ acc) {
    int t = blockIdx.x * blockDim.x + threadIdx.x;      // exact: 2*BATCH*8
    int b   = t >> 3;
    int sub = t & 7;
    int r   = (b < BATCH) ? uid[b] : (iid[b - BATCH] + NUM_USERS);
    uint4 g = ((const uint4*)(x + (long)r * D))[sub];
    const __half2* h = (const __half2*)&g;
    float4* ap = (float4*)(acc + (long)b * D) + sub * 2;
    float4 q0 = ap[0], q1 = ap[1];
    float2 f0 = __half22float2(h[0]); q0.x += f0.x; q0.y += f0.y;
    float2 f1 = __half22float2(h[1]); q0.z += f1.x; q0.w += f1.y;
    float2 f2 = __half22float2(h[2]); q1.x += f2.x; q1.y += f2.y;
    float2 f3 = __half22float2(h[3]); q1.z += f3.x; q1.w += f3.y;
    ap[0] = q0; ap[1] = q1;
}

// ---------------------------------------------------------------------------
// final: out[b] = dot(accU[b], accI[b]) / 16
// ---------------------------------------------------------------------------
__global__ void final_dot(const float* __restrict__ acc, float* __restrict__ out) {
    int t = blockIdx.x * blockDim.x + threadIdx.x;      // exact: BATCH*16
    int b   = t >> 4;
    int sub = t & 15;
    float4 u = *((const float4*)(acc + (long)b * D) + sub);
    float4 w = *((const float4*)(acc + (long)(b + BATCH) * D) + sub);
    float p = u.x * w.x + u.y * w.y + u.z * w.z + u.w * w.w;
    p += __shfl_xor(p, 1);
    p += __shfl_xor(p, 2);
    p += __shfl_xor(p, 4);
    p += __shfl_xor(p, 8);
    if (sub == 0) out[b] = p * (1.0f / 16.0f);
}

extern "C" void kernel_launch(void* const* d_in, const int* in_sizes, int n_in,
                              void* d_out, int out_size, void* d_ws, size_t ws_size,
                              hipStream_t stream) {
    const int*   user_ids = (const int*)d_in[0];
    const int*   item_ids = (const int*)d_in[1];
    const int*   adj_row  = (const int*)d_in[2];
    const int*   adj_col  = (const int*)d_in[3];
    const float* adj_val  = (const float*)d_in[4];
    const float* uw       = (const float*)d_in[5];
    const float* iw       = (const float*)d_in[6];
    float*       out      = (float*)d_out;

    // workspace bump allocator (256B aligned); total ~184 MB (<=195.6MB proven OK)
    char* ws = (char*)d_ws;
    size_t off = 0;
    auto alloc = [&](size_t bytes) {
        char* p = ws + off;
        off += (bytes + 255) & ~(size_t)255;
        return p;
    };
    const size_t xhbytes = (size_t)NT * D * sizeof(unsigned short);         // 38.4 MB
    const size_t ebytes  = (size_t)NSB * SBCAP * sizeof(int2);              // 38.4 MB
    unsigned short* x0h = (unsigned short*)alloc(xhbytes);
    unsigned short* xAh = (unsigned short*)alloc(xhbytes);
    unsigned short* xBh = (unsigned short*)alloc(ebytes > xhbytes ? ebytes : xhbytes);
    float* acc          = (float*)alloc((size_t)2 * BATCH * D * sizeof(float)); // 8.4 MB
    int*   rowstart     = (int*)alloc((size_t)NT * sizeof(int));
    int*   rowend       = (int*)alloc((size_t)NT * sizeof(int));
    int*   bcnt         = (int*)alloc((size_t)NSB * sizeof(int));
    char*  flags        = (char*)alloc((size_t)NT);
    int2*  cv           = (int2*)alloc((size_t)NSB * BSTRIDE * sizeof(int2)); // 57.6 MB
    int2*  entries      = (int2*)xBh;   // dead before xBh first written (layer 2)

    // ---- bucketed CSR build (padded rows, fixed bucket stride) ----
    hipMemsetAsync(bcnt, 0, (size_t)NSB * sizeof(int), stream);
    p1_bin<<<NCHUNK, 512, 0, stream>>>(adj_row, adj_col, adj_val, bcnt, entries);
    p2_csr<<<NSB, SB_ROWS, 0, stream>>>(bcnt, entries, rowstart, rowend, cv);

    // ---- needed-row flags for layer 2 ----
    hipMemsetAsync(flags, 0, (size_t)NT, stream);
    mark_needed<<<(2 * BATCH) / 256, 256, 0, stream>>>(user_ids, item_ids, rowstart, rowend,
                                                       cv, flags);

    // ---- layer pipeline (x stored fp16, accumulation fp32) ----
    init_x0<<<(NT * 8) / 256, 256, 0, stream>>>(uw, iw, x0h);
    gather_init<<<(2 * BATCH * 16) / 256, 256, 0, stream>>>(user_ids, item_ids, uw, iw, acc);

    // layer 1: x0h -> xAh (all rows)
    csr_spmm_h<false><<<(NT + 3) / 4, 256, 0, stream>>>(rowstart, rowend, cv, x0h, nullptr, xAh);
    gather_acc_h<<<(2 * BATCH * 8) / 256, 256, 0, stream>>>(user_ids, item_ids, xAh, acc);

    // layer 2: xAh -> xBh, only rows needed downstream (~78%)
    csr_spmm_h<true><<<(NT + 3) / 4, 256, 0, stream>>>(rowstart, rowend, cv, xAh, flags, xBh);
    gather_acc_h<<<(2 * BATCH * 8) / 256, 256, 0, stream>>>(user_ids, item_ids, xBh, acc);

    // layer 3: only the 2*BATCH batch rows, straight into fp32 acc
    csr_spmm_acc_h<<<(2 * BATCH + 3) / 4, 256, 0, stream>>>(user_ids, item_ids,
                                                            rowstart, rowend, cv, xBh, acc);

    final_dot<<<(BATCH * 16) / 256, 256, 0, stream>>>(acc, out);
}